// Round 1
// baseline (943.654 us; speedup 1.0000x reference)
//
#include <hip/hip_runtime.h>

#define HID 128
#define NH 8

__device__ __forceinline__ float dot4f(float4 a, float4 b) {
    return a.x*b.x + a.y*b.y + a.z*b.z + a.w*b.w;
}

// ---------------- histogram of destination rows ----------------
__global__ void k_hist(const int* __restrict__ row, int E, int* __restrict__ count) {
    int i = blockIdx.x * blockDim.x + threadIdx.x;
    int stride = gridDim.x * blockDim.x;
    for (; i < E; i += stride) atomicAdd(&count[row[i]], 1);
}

// ---------------- 3-phase exclusive scan (total <= 128*1024) ----------------
__global__ void k_scan1(const int* __restrict__ in, int total,
                        int* __restrict__ out, int* __restrict__ bsums) {
    __shared__ int sd[256];
    int t = threadIdx.x;
    int base = blockIdx.x * 1024 + t * 4;
    int v0 = (base + 0 < total) ? in[base + 0] : 0;
    int v1 = (base + 1 < total) ? in[base + 1] : 0;
    int v2 = (base + 2 < total) ? in[base + 2] : 0;
    int v3 = (base + 3 < total) ? in[base + 3] : 0;
    int s = v0 + v1 + v2 + v3;
    sd[t] = s; __syncthreads();
    for (int off = 1; off < 256; off <<= 1) {
        int xx = (t >= off) ? sd[t - off] : 0;
        __syncthreads();
        sd[t] += xx;
        __syncthreads();
    }
    int excl = sd[t] - s;
    if (t == 255) bsums[blockIdx.x] = sd[255];
    int run = excl;
    if (base + 0 < total) out[base + 0] = run; run += v0;
    if (base + 1 < total) out[base + 1] = run; run += v1;
    if (base + 2 < total) out[base + 2] = run; run += v2;
    if (base + 3 < total) out[base + 3] = run;
}

__global__ void k_scan2(int* __restrict__ bs, int nb) {
    __shared__ int sd[128];
    int t = threadIdx.x;
    int vv = (t < nb) ? bs[t] : 0;
    sd[t] = vv; __syncthreads();
    for (int off = 1; off < 128; off <<= 1) {
        int xx = (t >= off) ? sd[t - off] : 0;
        __syncthreads();
        sd[t] += xx;
        __syncthreads();
    }
    if (t < nb) bs[t] = sd[t] - vv;   // exclusive
}

__global__ void k_scan3(int* __restrict__ out, int total, const int* __restrict__ bs) {
    int add = bs[blockIdx.x];
    int base = blockIdx.x * 1024 + threadIdx.x * 4;
    #pragma unroll
    for (int i = 0; i < 4; ++i)
        if (base + i < total) out[base + i] += add;
}

// ---------------- scatter edge ids into per-node buckets ----------------
__global__ void k_scatter(const int* __restrict__ row, int E,
                          const int* __restrict__ start, int* __restrict__ cursor,
                          int* __restrict__ perm) {
    int i = blockIdx.x * blockDim.x + threadIdx.x;
    int stride = gridDim.x * blockDim.x;
    for (; i < E; i += stride) {
        int r = row[i];
        int p = start[r] + atomicAdd(&cursor[r], 1);
        perm[p] = i;
    }
}

// ---------------- QKV projection: q/k/v = x @ W.T + b ----------------
// tiles: 32 nodes x 64 cols, K=128 fully staged in LDS
__global__ __launch_bounds__(256) void k_qkv(
    const float* __restrict__ x,
    const float* __restrict__ qw, const float* __restrict__ kw, const float* __restrict__ vw,
    const float* __restrict__ qb, const float* __restrict__ kb, const float* __restrict__ vb,
    float* __restrict__ q, float* __restrict__ k, float* __restrict__ v, int n)
{
    __shared__ float As[32][132];
    __shared__ float Bs[64][132];
    int bid = blockIdx.x;
    int mb = bid / 6, cb = bid % 6;
    int m0 = mb * 32;
    int t = threadIdx.x;
    int which = cb >> 1;
    const float* W  = (which == 0) ? qw : (which == 1) ? kw : vw;
    const float* Bv = (which == 0) ? qb : (which == 1) ? kb : vb;
    float* O        = (which == 0) ? q  : (which == 1) ? k  : v;
    int wr0 = (cb & 1) * 64;

    #pragma unroll
    for (int p = 0; p < 4; ++p) {           // A: 32x128 floats
        int f = p * 256 + t;
        int r = f >> 5, c4 = (f & 31) * 4;
        float4 val = make_float4(0.f, 0.f, 0.f, 0.f);
        int node = m0 + r;
        if (node < n) val = *(const float4*)(x + (size_t)node * HID + c4);
        *(float4*)&As[r][c4] = val;
    }
    #pragma unroll
    for (int p = 0; p < 8; ++p) {           // B: 64x128 floats
        int f = p * 256 + t;
        int r = f >> 5, c4 = (f & 31) * 4;
        *(float4*)&Bs[r][c4] = *(const float4*)(W + (size_t)(wr0 + r) * HID + c4);
    }
    __syncthreads();

    int tx = t & 15, ty = t >> 4;
    float acc[2][4] = {{0.f,0.f,0.f,0.f},{0.f,0.f,0.f,0.f}};
    for (int kk = 0; kk < HID; kk += 4) {
        float4 a0 = *(const float4*)&As[ty * 2 + 0][kk];
        float4 a1 = *(const float4*)&As[ty * 2 + 1][kk];
        #pragma unroll
        for (int jj = 0; jj < 4; ++jj) {
            float4 b = *(const float4*)&Bs[tx + 16 * jj][kk];
            acc[0][jj] += dot4f(a0, b);
            acc[1][jj] += dot4f(a1, b);
        }
    }
    #pragma unroll
    for (int i = 0; i < 2; ++i) {
        int node = m0 + ty * 2 + i;
        if (node >= n) continue;
        #pragma unroll
        for (int jj = 0; jj < 4; ++jj) {
            int cl = wr0 + tx + 16 * jj;
            O[(size_t)node * HID + cl] = acc[i][jj] + Bv[cl];
        }
    }
}

// ---------------- edge bias: ebias[e,h] = edge_emb[e] . eb_w[h] + eb_b[h] ----------------
__global__ __launch_bounds__(256) void k_ebias(
    const float* __restrict__ emb, const float* __restrict__ ebw,
    const float* __restrict__ ebb, float* __restrict__ out, int E)
{
    __shared__ float Es[32][132];
    __shared__ float Ws[8][132];
    int e0 = blockIdx.x * 32;
    int t = threadIdx.x;
    #pragma unroll
    for (int p = 0; p < 4; ++p) {
        int f = p * 256 + t;
        int r = f >> 5, c4 = (f & 31) * 4;
        float4 val = make_float4(0.f, 0.f, 0.f, 0.f);
        if (e0 + r < E) val = *(const float4*)(emb + (size_t)(e0 + r) * HID + c4);
        *(float4*)&Es[r][c4] = val;
    }
    {   // eb_w: 8x128 = 256 float4, one per thread
        int r = t >> 5, c4 = (t & 31) * 4;
        *(float4*)&Ws[r][c4] = *(const float4*)(ebw + (size_t)r * HID + c4);
    }
    __syncthreads();
    int el = t >> 3, h = t & 7;
    float acc = 0.f;
    for (int c4 = 0; c4 < HID; c4 += 4) {
        float4 ev = *(const float4*)&Es[el][c4];
        float4 wv = *(const float4*)&Ws[h][c4];
        acc += dot4f(ev, wv);
    }
    if (e0 + el < E) out[(size_t)(e0 + el) * NH + h] = acc + ebb[h];
}

// ---------------- per-node attention: scores -> softmax -> weighted V ----------------
// one wave per node; 4 edge-slots x 16 lanes (lane j owns elements j*8..j*8+8, head j>>1)
__global__ __launch_bounds__(256) void k_attn(
    const float* __restrict__ q, const float* __restrict__ k, const float* __restrict__ v,
    const float* __restrict__ ebias, const int* __restrict__ col,
    const int* __restrict__ perm, const int* __restrict__ start,
    float* __restrict__ out, int n)
{
    int gtid = blockIdx.x * blockDim.x + threadIdx.x;
    int wave = gtid >> 6;
    int nw = (gridDim.x * blockDim.x) >> 6;
    int lane = threadIdx.x & 63;
    int slot = lane >> 4, j = lane & 15;

    for (int node = wave; node < n; node += nw) {
        const float4 q0 = *(const float4*)(q + (size_t)node * HID + j * 8);
        const float4 q1 = *(const float4*)(q + (size_t)node * HID + j * 8 + 4);
        int s0 = start[node];
        int deg = start[node + 1] - s0;
        float acc[8] = {0.f,0.f,0.f,0.f,0.f,0.f,0.f,0.f};
        float denom = 0.f;

        for (int base = 0; base < deg; base += 4) {
            int idx = base + slot;
            bool act = idx < deg;
            int e = 0;
            if (act) e = perm[s0 + idx];
            int c = col[e];
            const float4 k0 = *(const float4*)(k + (size_t)c * HID + j * 8);
            const float4 k1 = *(const float4*)(k + (size_t)c * HID + j * 8 + 4);
            const float4 v0 = *(const float4*)(v + (size_t)c * HID + j * 8);
            const float4 v1 = *(const float4*)(v + (size_t)c * HID + j * 8 + 4);
            float part = dot4f(q0, k0) + dot4f(q1, k1);
            part += __shfl_xor(part, 1);
            float sc = part * 0.25f + ebias[(size_t)e * NH + (j >> 1)];
            float es = act ? __expf(sc) : 0.f;
            denom += es;
            acc[0] += es * v0.x; acc[1] += es * v0.y; acc[2] += es * v0.z; acc[3] += es * v0.w;
            acc[4] += es * v1.x; acc[5] += es * v1.y; acc[6] += es * v1.z; acc[7] += es * v1.w;
        }
        #pragma unroll
        for (int off = 16; off < 64; off <<= 1) {
            denom += __shfl_xor(denom, off);
            #pragma unroll
            for (int i = 0; i < 8; ++i) acc[i] += __shfl_xor(acc[i], off);
        }
        if (slot == 0) {
            float inv = 1.f / (denom + 1e-10f);
            float4 o0 = make_float4(acc[0]*inv, acc[1]*inv, acc[2]*inv, acc[3]*inv);
            float4 o1 = make_float4(acc[4]*inv, acc[5]*inv, acc[6]*inv, acc[7]*inv);
            *(float4*)(out + (size_t)node * HID + j * 8)     = o0;
            *(float4*)(out + (size_t)node * HID + j * 8 + 4) = o1;
        }
    }
}

// ---------------- final projection, in place on d_out ----------------
// tile 32 rows x all 128 cols; B (out_w) staged in two 64-col halves
__global__ __launch_bounds__(256) void k_outproj(
    float* __restrict__ io, const float* __restrict__ ow, const float* __restrict__ ob, int n)
{
    __shared__ float As[32][132];
    __shared__ float Bs[64][132];
    int m0 = blockIdx.x * 32;
    int t = threadIdx.x;
    #pragma unroll
    for (int p = 0; p < 4; ++p) {
        int f = p * 256 + t;
        int r = f >> 5, c4 = (f & 31) * 4;
        float4 val = make_float4(0.f, 0.f, 0.f, 0.f);
        if (m0 + r < n) val = *(const float4*)(io + (size_t)(m0 + r) * HID + c4);
        *(float4*)&As[r][c4] = val;
    }
    int tx = t & 15, ty = t >> 4;
    float acc[2][8];
    #pragma unroll
    for (int i = 0; i < 2; ++i)
        #pragma unroll
        for (int jj = 0; jj < 8; ++jj) acc[i][jj] = 0.f;

    for (int half = 0; half < 2; ++half) {
        __syncthreads();
        #pragma unroll
        for (int p = 0; p < 8; ++p) {
            int f = p * 256 + t;
            int r = f >> 5, c4 = (f & 31) * 4;
            *(float4*)&Bs[r][c4] = *(const float4*)(ow + (size_t)(half * 64 + r) * HID + c4);
        }
        __syncthreads();
        for (int kk = 0; kk < HID; kk += 4) {
            float4 a0 = *(const float4*)&As[ty * 2 + 0][kk];
            float4 a1 = *(const float4*)&As[ty * 2 + 1][kk];
            #pragma unroll
            for (int jj = 0; jj < 4; ++jj) {
                float4 b = *(const float4*)&Bs[tx + 16 * jj][kk];
                acc[0][half * 4 + jj] += dot4f(a0, b);
                acc[1][half * 4 + jj] += dot4f(a1, b);
            }
        }
    }
    #pragma unroll
    for (int i = 0; i < 2; ++i) {
        int node = m0 + ty * 2 + i;
        if (node >= n) continue;
        #pragma unroll
        for (int half = 0; half < 2; ++half)
            #pragma unroll
            for (int jj = 0; jj < 4; ++jj) {
                int cl = half * 64 + tx + 16 * jj;
                io[(size_t)node * HID + cl] = acc[i][half * 4 + jj] + ob[cl];
            }
    }
}

extern "C" void kernel_launch(void* const* d_in, const int* in_sizes, int n_in,
                              void* d_out, int out_size, void* d_ws, size_t ws_size,
                              hipStream_t stream) {
    const float* x   = (const float*)d_in[0];
    const int*   eix = (const int*)  d_in[1];
    const float* emb = (const float*)d_in[2];
    const float* qw  = (const float*)d_in[3];
    const float* qb  = (const float*)d_in[4];
    const float* kw  = (const float*)d_in[5];
    const float* kb  = (const float*)d_in[6];
    const float* vw  = (const float*)d_in[7];
    const float* vb  = (const float*)d_in[8];
    const float* ow  = (const float*)d_in[9];
    const float* ob  = (const float*)d_in[10];
    const float* ebw = (const float*)d_in[11];
    const float* ebb = (const float*)d_in[12];

    int n = in_sizes[0] / HID;
    int E = in_sizes[2] / HID;
    const int* row = eix;
    const int* col = eix + E;

    char* ws = (char*)d_ws;
    float* q     = (float*)ws; ws += (size_t)n * HID * 4;
    float* k     = (float*)ws; ws += (size_t)n * HID * 4;
    float* v     = (float*)ws; ws += (size_t)n * HID * 4;
    float* ebias = (float*)ws; ws += (size_t)E * NH * 4;
    int* count   = (int*)ws;   ws += (size_t)(n + 2) * 4;
    int* startp  = (int*)ws;   ws += (size_t)(n + 2) * 4;
    int* bsums   = (int*)ws;   ws += 256 * 4;
    int* cursor  = (int*)ws;   ws += (size_t)n * 4;
    int* perm    = (int*)ws;   ws += (size_t)E * 4;

    hipMemsetAsync(count, 0, (size_t)(n + 1) * sizeof(int), stream);
    hipMemsetAsync(cursor, 0, (size_t)n * sizeof(int), stream);

    k_hist<<<1024, 256, 0, stream>>>(row, E, count);

    int total = n + 1;
    int nb = (total + 1023) / 1024;
    k_scan1<<<nb, 256, 0, stream>>>(count, total, startp, bsums);
    k_scan2<<<1, 128, 0, stream>>>(bsums, nb);
    k_scan3<<<nb, 256, 0, stream>>>(startp, total, bsums);

    k_scatter<<<1024, 256, 0, stream>>>(row, E, startp, cursor, perm);

    k_qkv<<<((n + 31) / 32) * 6, 256, 0, stream>>>(x, qw, kw, vw, qb, kb, vb, q, k, v, n);
    k_ebias<<<(E + 31) / 32, 256, 0, stream>>>(emb, ebw, ebb, ebias, E);
    k_attn<<<1024, 256, 0, stream>>>(q, k, v, ebias, col, perm, startp, (float*)d_out, n);
    k_outproj<<<(n + 31) / 32, 256, 0, stream>>>((float*)d_out, ow, ob, n);
}

// Round 2
// 628.672 us; speedup vs baseline: 1.5010x; 1.5010x over previous
//
#include <hip/hip_runtime.h>

#define HID 128
#define NH 8

typedef __attribute__((ext_vector_type(8))) short short8;
typedef __attribute__((ext_vector_type(4))) float f32x4;

__device__ __forceinline__ float dot4f(float4 a, float4 b) {
    return a.x*b.x + a.y*b.y + a.z*b.z + a.w*b.w;
}
__device__ __forceinline__ unsigned short f2bf(float f) {
    unsigned int u = __float_as_uint(f);
    u = (u + 0x7FFF + ((u >> 16) & 1)) >> 16;
    return (unsigned short)u;
}
__device__ __forceinline__ float bf2f(unsigned short s) {
    return __uint_as_float((unsigned int)s << 16);
}

// ---------------- histogram of destination rows ----------------
__global__ void k_hist(const int* __restrict__ row, int E, int* __restrict__ count) {
    int i = blockIdx.x * blockDim.x + threadIdx.x;
    int stride = gridDim.x * blockDim.x;
    for (; i < E; i += stride) atomicAdd(&count[row[i]], 1);
}

// ---------------- 3-phase exclusive scan (total <= 128*1024) ----------------
__global__ void k_scan1(const int* __restrict__ in, int total,
                        int* __restrict__ out, int* __restrict__ bsums) {
    __shared__ int sd[256];
    int t = threadIdx.x;
    int base = blockIdx.x * 1024 + t * 4;
    int v0 = (base + 0 < total) ? in[base + 0] : 0;
    int v1 = (base + 1 < total) ? in[base + 1] : 0;
    int v2 = (base + 2 < total) ? in[base + 2] : 0;
    int v3 = (base + 3 < total) ? in[base + 3] : 0;
    int s = v0 + v1 + v2 + v3;
    sd[t] = s; __syncthreads();
    for (int off = 1; off < 256; off <<= 1) {
        int xx = (t >= off) ? sd[t - off] : 0;
        __syncthreads();
        sd[t] += xx;
        __syncthreads();
    }
    int excl = sd[t] - s;
    if (t == 255) bsums[blockIdx.x] = sd[255];
    int run = excl;
    if (base + 0 < total) out[base + 0] = run; run += v0;
    if (base + 1 < total) out[base + 1] = run; run += v1;
    if (base + 2 < total) out[base + 2] = run; run += v2;
    if (base + 3 < total) out[base + 3] = run;
}

__global__ void k_scan2(int* __restrict__ bs, int nb) {
    __shared__ int sd[128];
    int t = threadIdx.x;
    int vv = (t < nb) ? bs[t] : 0;
    sd[t] = vv; __syncthreads();
    for (int off = 1; off < 128; off <<= 1) {
        int xx = (t >= off) ? sd[t - off] : 0;
        __syncthreads();
        sd[t] += xx;
        __syncthreads();
    }
    if (t < nb) bs[t] = sd[t] - vv;   // exclusive
}

__global__ void k_scan3(int* __restrict__ out, int total, const int* __restrict__ bs) {
    int add = bs[blockIdx.x];
    int base = blockIdx.x * 1024 + threadIdx.x * 4;
    #pragma unroll
    for (int i = 0; i < 4; ++i)
        if (base + i < total) out[base + i] += add;
}

// ---------------- scatter: build pos[] (edge -> sorted slot) and col_sorted ----------------
__global__ void k_scatter(const int* __restrict__ row, const int* __restrict__ col, int E,
                          const int* __restrict__ start, int* __restrict__ cursor,
                          int* __restrict__ pos, int* __restrict__ col_sorted) {
    int i = blockIdx.x * blockDim.x + threadIdx.x;
    int stride = gridDim.x * blockDim.x;
    for (; i < E; i += stride) {
        int r = row[i];
        int p = start[r] + atomicAdd(&cursor[r], 1);
        pos[i] = p;
        col_sorted[p] = col[i];
    }
}

// ---------------- convert the 4 weight matrices to bf16 ----------------
__global__ void k_cvtw(const float* __restrict__ qw, const float* __restrict__ kw,
                       const float* __restrict__ vw, const float* __restrict__ ow,
                       unsigned short* __restrict__ wbf) {
    int i = blockIdx.x * 256 + threadIdx.x;   // 16384 threads, 4 elems each
    int idx = i * 4;
    int m = idx >> 14;
    int off = idx & 16383;
    const float* src = (m == 0) ? qw : (m == 1) ? kw : (m == 2) ? vw : ow;
    float4 v = *(const float4*)(src + off);
    ushort4 o;
    o.x = f2bf(v.x); o.y = f2bf(v.y); o.z = f2bf(v.z); o.w = f2bf(v.w);
    *(ushort4*)(wbf + idx) = o;
}

// ---------------- QKV projection via bf16 MFMA: qkv[node][384] bf16 ----------------
__global__ __launch_bounds__(256) void k_qkv_mfma(
    const float* __restrict__ x, const unsigned short* __restrict__ wbf,
    const float* __restrict__ qb, const float* __restrict__ kb, const float* __restrict__ vb,
    unsigned short* __restrict__ qkvbf, int n)
{
    __shared__ unsigned short xs[64][136];
    int t = threadIdx.x;
    int m0 = blockIdx.x * 64;
    #pragma unroll
    for (int p = 0; p < 2; ++p) {               // stage 64x128 f32 -> bf16 LDS
        int f = p * 256 + t;
        int r = f >> 3;
        int c16 = (f & 7) * 16;
        int node = m0 + r;
        float4 u0 = {0,0,0,0}, u1 = {0,0,0,0}, u2 = {0,0,0,0}, u3 = {0,0,0,0};
        if (node < n) {
            const float4* px = (const float4*)(x + (size_t)node * HID + c16);
            u0 = px[0]; u1 = px[1]; u2 = px[2]; u3 = px[3];
        }
        union { unsigned short u[8]; short8 v; } a, b;
        a.u[0]=f2bf(u0.x); a.u[1]=f2bf(u0.y); a.u[2]=f2bf(u0.z); a.u[3]=f2bf(u0.w);
        a.u[4]=f2bf(u1.x); a.u[5]=f2bf(u1.y); a.u[6]=f2bf(u1.z); a.u[7]=f2bf(u1.w);
        b.u[0]=f2bf(u2.x); b.u[1]=f2bf(u2.y); b.u[2]=f2bf(u2.z); b.u[3]=f2bf(u2.w);
        b.u[4]=f2bf(u3.x); b.u[5]=f2bf(u3.y); b.u[6]=f2bf(u3.z); b.u[7]=f2bf(u3.w);
        *(short8*)&xs[r][c16]     = a.v;
        *(short8*)&xs[r][c16 + 8] = b.v;
    }
    __syncthreads();

    int w = t >> 6, l = t & 63;
    int lr = l & 15, lc = l >> 4;
    short8 afr[4];
    #pragma unroll
    for (int c = 0; c < 4; ++c)
        afr[c] = *(const short8*)&xs[w * 16 + lr][c * 32 + lc * 8];

    #pragma unroll
    for (int m = 0; m < 3; ++m) {
        const float* bias = (m == 0) ? qb : (m == 1) ? kb : vb;
        #pragma unroll
        for (int ct = 0; ct < 8; ++ct) {
            int colg = ct * 16 + lr;
            f32x4 acc = {0.f, 0.f, 0.f, 0.f};
            const unsigned short* wrow = wbf + (size_t)m * 16384 + (size_t)colg * 128 + lc * 8;
            #pragma unroll
            for (int c = 0; c < 4; ++c) {
                short8 bfr = *(const short8*)(wrow + c * 32);
                acc = __builtin_amdgcn_mfma_f32_16x16x32_bf16(afr[c], bfr, acc, 0, 0, 0);
            }
            float bv = bias[colg];
            #pragma unroll
            for (int r = 0; r < 4; ++r) {
                int node = m0 + w * 16 + lc * 4 + r;
                if (node < n)
                    qkvbf[(size_t)node * 384 + m * 128 + colg] = f2bf(acc[r] + bv);
            }
        }
    }
}

// ---------------- edge bias streamed in edge order, written in sorted order ----------------
__global__ __launch_bounds__(256) void k_ebias(
    const float* __restrict__ emb, const float* __restrict__ ebw,
    const float* __restrict__ ebb, const int* __restrict__ pos,
    float* __restrict__ out, int E)
{
    __shared__ float Es[32][132];
    __shared__ float Ws[8][132];
    int e0 = blockIdx.x * 32;
    int t = threadIdx.x;
    #pragma unroll
    for (int p = 0; p < 4; ++p) {
        int f = p * 256 + t;
        int r = f >> 5, c4 = (f & 31) * 4;
        float4 val = make_float4(0.f, 0.f, 0.f, 0.f);
        if (e0 + r < E) val = *(const float4*)(emb + (size_t)(e0 + r) * HID + c4);
        *(float4*)&Es[r][c4] = val;
    }
    {
        int r = t >> 5, c4 = (t & 31) * 4;
        *(float4*)&Ws[r][c4] = *(const float4*)(ebw + (size_t)r * HID + c4);
    }
    __syncthreads();
    int el = t >> 3, h = t & 7;
    float acc = 0.f;
    for (int c4 = 0; c4 < HID; c4 += 4) {
        float4 ev = *(const float4*)&Es[el][c4];
        float4 wv = *(const float4*)&Ws[h][c4];
        acc += dot4f(ev, wv);
    }
    int e = e0 + el;
    if (e < E) out[(size_t)pos[e] * NH + h] = acc + ebb[h];
}

// ---------------- per-node attention over sorted edges, bf16 kv gather ----------------
__global__ __launch_bounds__(256) void k_attn(
    const unsigned short* __restrict__ qkvbf, const float* __restrict__ ebs,
    const int* __restrict__ cols, const int* __restrict__ start,
    float* __restrict__ out, int n, int E)
{
    int node = blockIdx.x * 4 + (threadIdx.x >> 6);
    if (node >= n) return;
    int l = threadIdx.x & 63;
    int slot = l >> 4, j = l & 15;
    int s0 = start[node];
    int deg = start[node + 1] - s0;

    float qf[8];
    {
        short8 qv = *(const short8*)(qkvbf + (size_t)node * 384 + j * 8);
        #pragma unroll
        for (int i = 0; i < 8; ++i) qf[i] = bf2f((unsigned short)qv[i]);
    }
    int colv = 0;
    if (l < deg && s0 + l < E) colv = cols[s0 + l];

    float acc[8] = {0.f,0.f,0.f,0.f,0.f,0.f,0.f,0.f};
    float denom = 0.f;

    for (int base = 0; base < deg; base += 4) {
        int idx = base + slot;
        bool act = idx < deg;
        int c = (idx < 64) ? __shfl(colv, idx) : (act ? cols[s0 + idx] : 0);
        const unsigned short* kv = qkvbf + (size_t)c * 384 + 128 + j * 8;
        short8 kk = *(const short8*)kv;
        short8 vv = *(const short8*)(kv + 128);
        float part = 0.f;
        #pragma unroll
        for (int i = 0; i < 8; ++i) part += qf[i] * bf2f((unsigned short)kk[i]);
        part += __shfl_xor(part, 1);
        float eb = act ? ebs[(size_t)(s0 + idx) * NH + (j >> 1)] : 0.f;
        float sc = part * 0.25f + eb;
        float es = act ? __expf(sc) : 0.f;
        denom += es;
        #pragma unroll
        for (int i = 0; i < 8; ++i) acc[i] += es * bf2f((unsigned short)vv[i]);
    }
    #pragma unroll
    for (int off = 16; off < 64; off <<= 1) {
        denom += __shfl_xor(denom, off);
        #pragma unroll
        for (int i = 0; i < 8; ++i) acc[i] += __shfl_xor(acc[i], off);
    }
    if (slot == 0) {
        float inv = 1.f / (denom + 1e-10f);
        float4 o0 = make_float4(acc[0]*inv, acc[1]*inv, acc[2]*inv, acc[3]*inv);
        float4 o1 = make_float4(acc[4]*inv, acc[5]*inv, acc[6]*inv, acc[7]*inv);
        *(float4*)(out + (size_t)node * HID + j * 8)     = o0;
        *(float4*)(out + (size_t)node * HID + j * 8 + 4) = o1;
    }
}

// ---------------- final projection via bf16 MFMA, in place on d_out ----------------
__global__ __launch_bounds__(256) void k_outproj_mfma(
    float* __restrict__ io, const unsigned short* __restrict__ wbf,
    const float* __restrict__ ob, int n)
{
    __shared__ unsigned short hs[64][136];
    int t = threadIdx.x;
    int m0 = blockIdx.x * 64;
    #pragma unroll
    for (int p = 0; p < 2; ++p) {
        int f = p * 256 + t;
        int r = f >> 3;
        int c16 = (f & 7) * 16;
        int node = m0 + r;
        float4 u0 = {0,0,0,0}, u1 = {0,0,0,0}, u2 = {0,0,0,0}, u3 = {0,0,0,0};
        if (node < n) {
            const float4* px = (const float4*)(io + (size_t)node * HID + c16);
            u0 = px[0]; u1 = px[1]; u2 = px[2]; u3 = px[3];
        }
        union { unsigned short u[8]; short8 v; } a, b;
        a.u[0]=f2bf(u0.x); a.u[1]=f2bf(u0.y); a.u[2]=f2bf(u0.z); a.u[3]=f2bf(u0.w);
        a.u[4]=f2bf(u1.x); a.u[5]=f2bf(u1.y); a.u[6]=f2bf(u1.z); a.u[7]=f2bf(u1.w);
        b.u[0]=f2bf(u2.x); b.u[1]=f2bf(u2.y); b.u[2]=f2bf(u2.z); b.u[3]=f2bf(u2.w);
        b.u[4]=f2bf(u3.x); b.u[5]=f2bf(u3.y); b.u[6]=f2bf(u3.z); b.u[7]=f2bf(u3.w);
        *(short8*)&hs[r][c16]     = a.v;
        *(short8*)&hs[r][c16 + 8] = b.v;
    }
    __syncthreads();

    int w = t >> 6, l = t & 63;
    int lr = l & 15, lc = l >> 4;
    short8 afr[4];
    #pragma unroll
    for (int c = 0; c < 4; ++c)
        afr[c] = *(const short8*)&hs[w * 16 + lr][c * 32 + lc * 8];

    #pragma unroll
    for (int ct = 0; ct < 8; ++ct) {
        int colg = ct * 16 + lr;
        f32x4 acc = {0.f, 0.f, 0.f, 0.f};
        const unsigned short* wrow = wbf + (size_t)3 * 16384 + (size_t)colg * 128 + lc * 8;
        #pragma unroll
        for (int c = 0; c < 4; ++c) {
            short8 bfr = *(const short8*)(wrow + c * 32);
            acc = __builtin_amdgcn_mfma_f32_16x16x32_bf16(afr[c], bfr, acc, 0, 0, 0);
        }
        float bv = ob[colg];
        #pragma unroll
        for (int r = 0; r < 4; ++r) {
            int node = m0 + w * 16 + lc * 4 + r;
            if (node < n)
                io[(size_t)node * HID + colg] = acc[r] + bv;
        }
    }
}

extern "C" void kernel_launch(void* const* d_in, const int* in_sizes, int n_in,
                              void* d_out, int out_size, void* d_ws, size_t ws_size,
                              hipStream_t stream) {
    const float* x   = (const float*)d_in[0];
    const int*   eix = (const int*)  d_in[1];
    const float* emb = (const float*)d_in[2];
    const float* qw  = (const float*)d_in[3];
    const float* qb  = (const float*)d_in[4];
    const float* kw  = (const float*)d_in[5];
    const float* kb  = (const float*)d_in[6];
    const float* vw  = (const float*)d_in[7];
    const float* vb  = (const float*)d_in[8];
    const float* ow  = (const float*)d_in[9];
    const float* ob  = (const float*)d_in[10];
    const float* ebw = (const float*)d_in[11];
    const float* ebb = (const float*)d_in[12];

    int n = in_sizes[0] / HID;
    int E = in_sizes[2] / HID;
    const int* row = eix;
    const int* col = eix + E;

    char* wsp = (char*)d_ws;
    auto alloc = [&](size_t bytes) -> void* {
        void* p = (void*)wsp;
        wsp += (bytes + 255) & ~(size_t)255;
        return p;
    };
    unsigned short* qkvbf = (unsigned short*)alloc((size_t)n * 384 * 2);
    unsigned short* wbf   = (unsigned short*)alloc((size_t)4 * 16384 * 2);
    float* ebias_s        = (float*)alloc((size_t)E * NH * 4);
    int* count            = (int*)alloc((size_t)(n + 2) * 4);
    int* startp           = (int*)alloc((size_t)(n + 2) * 4);
    int* bsums            = (int*)alloc(256 * 4);
    int* cursor           = (int*)alloc((size_t)n * 4);
    int* pos              = (int*)alloc((size_t)E * 4);
    int* col_sorted       = (int*)alloc((size_t)E * 4);

    hipMemsetAsync(count, 0, (size_t)(n + 1) * sizeof(int), stream);
    hipMemsetAsync(cursor, 0, (size_t)n * sizeof(int), stream);

    k_cvtw<<<64, 256, 0, stream>>>(qw, kw, vw, ow, wbf);
    k_hist<<<1024, 256, 0, stream>>>(row, E, count);

    int total = n + 1;
    int nb = (total + 1023) / 1024;
    k_scan1<<<nb, 256, 0, stream>>>(count, total, startp, bsums);
    k_scan2<<<1, 128, 0, stream>>>(bsums, nb);
    k_scan3<<<nb, 256, 0, stream>>>(startp, total, bsums);

    k_scatter<<<1024, 256, 0, stream>>>(row, col, E, startp, cursor, pos, col_sorted);

    k_qkv_mfma<<<(n + 63) / 64, 256, 0, stream>>>(x, wbf, qb, kb, vb, qkvbf, n);
    k_ebias<<<(E + 31) / 32, 256, 0, stream>>>(emb, ebw, ebb, pos, ebias_s, E);
    k_attn<<<(n + 3) / 4, 256, 0, stream>>>(qkvbf, ebias_s, col_sorted, startp,
                                            (float*)d_out, n, E);
    k_outproj_mfma<<<(n + 63) / 64, 256, 0, stream>>>((float*)d_out, wbf, ob, n);
}

// Round 3
// 570.520 us; speedup vs baseline: 1.6540x; 1.1019x over previous
//
#include <hip/hip_runtime.h>

#define HID 128
#define NH 8

typedef __attribute__((ext_vector_type(8))) short short8;
typedef __attribute__((ext_vector_type(4))) float f32x4;

__device__ __forceinline__ unsigned short f2bf(float f) {
    unsigned int u = __float_as_uint(f);
    u = (u + 0x7FFF + ((u >> 16) & 1)) >> 16;
    return (unsigned short)u;
}
__device__ __forceinline__ float bf2f(unsigned short s) {
    return __uint_as_float((unsigned int)s << 16);
}

// ---------------- histogram of destination rows ----------------
__global__ void k_hist(const int* __restrict__ row, int E, int* __restrict__ count) {
    int i = blockIdx.x * blockDim.x + threadIdx.x;
    int stride = gridDim.x * blockDim.x;
    for (; i < E; i += stride) atomicAdd(&count[row[i]], 1);
}

// ---------------- 3-phase exclusive scan ----------------
__global__ void k_scan1(const int* __restrict__ in, int total,
                        int* __restrict__ out, int* __restrict__ bsums) {
    __shared__ int sd[256];
    int t = threadIdx.x;
    int base = blockIdx.x * 1024 + t * 4;
    int v0 = (base + 0 < total) ? in[base + 0] : 0;
    int v1 = (base + 1 < total) ? in[base + 1] : 0;
    int v2 = (base + 2 < total) ? in[base + 2] : 0;
    int v3 = (base + 3 < total) ? in[base + 3] : 0;
    int s = v0 + v1 + v2 + v3;
    sd[t] = s; __syncthreads();
    for (int off = 1; off < 256; off <<= 1) {
        int xx = (t >= off) ? sd[t - off] : 0;
        __syncthreads();
        sd[t] += xx;
        __syncthreads();
    }
    int excl = sd[t] - s;
    if (t == 255) bsums[blockIdx.x] = sd[255];
    int run = excl;
    if (base + 0 < total) out[base + 0] = run; run += v0;
    if (base + 1 < total) out[base + 1] = run; run += v1;
    if (base + 2 < total) out[base + 2] = run; run += v2;
    if (base + 3 < total) out[base + 3] = run;
}

__global__ void k_scan2(int* __restrict__ bs, int nb) {
    __shared__ int sd[128];
    int t = threadIdx.x;
    int vv = (t < nb) ? bs[t] : 0;
    sd[t] = vv; __syncthreads();
    for (int off = 1; off < 128; off <<= 1) {
        int xx = (t >= off) ? sd[t - off] : 0;
        __syncthreads();
        sd[t] += xx;
        __syncthreads();
    }
    if (t < nb) bs[t] = sd[t] - vv;   // exclusive
}

__global__ void k_scan3(int* __restrict__ out, int total, const int* __restrict__ bs) {
    int add = bs[blockIdx.x];
    int base = blockIdx.x * 1024 + threadIdx.x * 4;
    #pragma unroll
    for (int i = 0; i < 4; ++i)
        if (base + i < total) out[base + i] += add;
}

// ---------------- fused: edge-bias GEMV + sorted scatter of (col, bias) ----------------
// 8 lanes per edge; lane g owns cols [g*16, g*16+16); weights in registers-from-LDS
// with permuted layout Wx[h][c][g][4] so each ds_read_b128 is 8x16B contiguous.
__global__ __launch_bounds__(256) void k_edge_fused(
    const int* __restrict__ row, const int* __restrict__ col,
    const float* __restrict__ emb, const float* __restrict__ ebw,
    const float* __restrict__ ebb, const int* __restrict__ start,
    int* __restrict__ cursor, int* __restrict__ col_sorted,
    float* __restrict__ ebias_s, int E)
{
    __shared__ float Wx[8][4][8][4];   // [h][c][g][j] = ebw[h*128 + g*16 + c*4 + j]
    __shared__ float bb[8];
    int t = threadIdx.x;
    for (int i = t; i < 1024; i += 256) {
        int j = i & 3, g = (i >> 2) & 7, c = (i >> 5) & 3, h = i >> 7;
        Wx[h][c][g][j] = ebw[h * 128 + g * 16 + c * 4 + j];
    }
    if (t < 8) bb[t] = ebb[t];
    __syncthreads();

    int l = t & 63;
    int g = l & 7;        // column-chunk group
    int sub = l >> 3;     // edge within wave's group of 8
    int wid = blockIdx.x * 4 + (t >> 6);
    int nwaves = gridDim.x * 4;

    for (int base = wid * 8; base < E; base += nwaves * 8) {
        int e = base + sub;
        bool act = e < E;
        float p[8] = {0.f,0.f,0.f,0.f,0.f,0.f,0.f,0.f};
        if (act) {
            const float4* pe = (const float4*)(emb + (size_t)e * HID + g * 16);
            #pragma unroll
            for (int c = 0; c < 4; ++c) {
                float4 ev = pe[c];
                #pragma unroll
                for (int h = 0; h < 8; ++h) {
                    float4 wv = *(const float4*)&Wx[h][c][g][0];
                    p[h] += ev.x*wv.x + ev.y*wv.y + ev.z*wv.z + ev.w*wv.w;
                }
            }
        }
        // butterfly over the 8 lanes of this edge: every lane ends with all 8 head sums
        #pragma unroll
        for (int off = 1; off < 8; off <<= 1) {
            #pragma unroll
            for (int h = 0; h < 8; ++h) p[h] += __shfl_xor(p[h], off);
        }
        int pslot = 0;
        if (act && g == 0) {
            int r = row[e];
            pslot = start[r] + atomicAdd(&cursor[r], 1);
            col_sorted[pslot] = col[e];
        }
        pslot = __shfl(pslot, l & 56);   // broadcast from lane sub*8
        if (act) ebias_s[(size_t)pslot * NH + g] = p[g] + bb[g];
    }
}

// ---------------- convert the 4 weight matrices to bf16 ----------------
__global__ void k_cvtw(const float* __restrict__ qw, const float* __restrict__ kw,
                       const float* __restrict__ vw, const float* __restrict__ ow,
                       unsigned short* __restrict__ wbf) {
    int i = blockIdx.x * 256 + threadIdx.x;
    int idx = i * 4;
    int m = idx >> 14;
    int off = idx & 16383;
    const float* src = (m == 0) ? qw : (m == 1) ? kw : (m == 2) ? vw : ow;
    float4 v = *(const float4*)(src + off);
    ushort4 o;
    o.x = f2bf(v.x); o.y = f2bf(v.y); o.z = f2bf(v.z); o.w = f2bf(v.w);
    *(ushort4*)(wbf + idx) = o;
}

// ---------------- QKV projection via bf16 MFMA: qkv[node][384] bf16 ----------------
__global__ __launch_bounds__(256) void k_qkv_mfma(
    const float* __restrict__ x, const unsigned short* __restrict__ wbf,
    const float* __restrict__ qb, const float* __restrict__ kb, const float* __restrict__ vb,
    unsigned short* __restrict__ qkvbf, int n)
{
    __shared__ unsigned short xs[64][136];
    int t = threadIdx.x;
    int m0 = blockIdx.x * 64;
    #pragma unroll
    for (int p = 0; p < 2; ++p) {
        int f = p * 256 + t;
        int r = f >> 3;
        int c16 = (f & 7) * 16;
        int node = m0 + r;
        float4 u0 = {0,0,0,0}, u1 = {0,0,0,0}, u2 = {0,0,0,0}, u3 = {0,0,0,0};
        if (node < n) {
            const float4* px = (const float4*)(x + (size_t)node * HID + c16);
            u0 = px[0]; u1 = px[1]; u2 = px[2]; u3 = px[3];
        }
        union { unsigned short u[8]; short8 v; } a, b;
        a.u[0]=f2bf(u0.x); a.u[1]=f2bf(u0.y); a.u[2]=f2bf(u0.z); a.u[3]=f2bf(u0.w);
        a.u[4]=f2bf(u1.x); a.u[5]=f2bf(u1.y); a.u[6]=f2bf(u1.z); a.u[7]=f2bf(u1.w);
        b.u[0]=f2bf(u2.x); b.u[1]=f2bf(u2.y); b.u[2]=f2bf(u2.z); b.u[3]=f2bf(u2.w);
        b.u[4]=f2bf(u3.x); b.u[5]=f2bf(u3.y); b.u[6]=f2bf(u3.z); b.u[7]=f2bf(u3.w);
        *(short8*)&xs[r][c16]     = a.v;
        *(short8*)&xs[r][c16 + 8] = b.v;
    }
    __syncthreads();

    int w = t >> 6, l = t & 63;
    int lr = l & 15, lc = l >> 4;
    short8 afr[4];
    #pragma unroll
    for (int c = 0; c < 4; ++c)
        afr[c] = *(const short8*)&xs[w * 16 + lr][c * 32 + lc * 8];

    #pragma unroll
    for (int m = 0; m < 3; ++m) {
        const float* bias = (m == 0) ? qb : (m == 1) ? kb : vb;
        #pragma unroll
        for (int ct = 0; ct < 8; ++ct) {
            int colg = ct * 16 + lr;
            f32x4 acc = {0.f, 0.f, 0.f, 0.f};
            const unsigned short* wrow = wbf + (size_t)m * 16384 + (size_t)colg * 128 + lc * 8;
            #pragma unroll
            for (int c = 0; c < 4; ++c) {
                short8 bfr = *(const short8*)(wrow + c * 32);
                acc = __builtin_amdgcn_mfma_f32_16x16x32_bf16(afr[c], bfr, acc, 0, 0, 0);
            }
            float bv = bias[colg];
            #pragma unroll
            for (int r = 0; r < 4; ++r) {
                int node = m0 + w * 16 + lc * 4 + r;
                if (node < n)
                    qkvbf[(size_t)node * 384 + m * 128 + colg] = f2bf(acc[r] + bv);
            }
        }
    }
}

// ---------------- per-node attention over sorted edges, bf16 kv gather ----------------
__global__ __launch_bounds__(256) void k_attn(
    const unsigned short* __restrict__ qkvbf, const float* __restrict__ ebs,
    const int* __restrict__ cols, const int* __restrict__ start,
    float* __restrict__ out, int n, int E)
{
    int node = blockIdx.x * 4 + (threadIdx.x >> 6);
    if (node >= n) return;
    int l = threadIdx.x & 63;
    int slot = l >> 4, j = l & 15;
    int s0 = start[node];
    int deg = start[node + 1] - s0;

    float qf[8];
    {
        short8 qv = *(const short8*)(qkvbf + (size_t)node * 384 + j * 8);
        #pragma unroll
        for (int i = 0; i < 8; ++i) qf[i] = bf2f((unsigned short)qv[i]);
    }
    int colv = 0;
    if (l < deg) colv = cols[s0 + l];

    float acc[8] = {0.f,0.f,0.f,0.f,0.f,0.f,0.f,0.f};
    float denom = 0.f;

    for (int base = 0; base < deg; base += 4) {
        int idx = base + slot;
        bool act = idx < deg;
        int c = (idx < 64) ? __shfl(colv, idx) : (act ? cols[s0 + idx] : 0);
        const unsigned short* kv = qkvbf + (size_t)c * 384 + 128 + j * 8;
        short8 kk = *(const short8*)kv;
        short8 vv = *(const short8*)(kv + 128);
        float part = 0.f;
        #pragma unroll
        for (int i = 0; i < 8; ++i) part += qf[i] * bf2f((unsigned short)kk[i]);
        part += __shfl_xor(part, 1);
        float eb = act ? ebs[(size_t)(s0 + idx) * NH + (j >> 1)] : 0.f;
        float sc = part * 0.25f + eb;
        float es = act ? __expf(sc) : 0.f;
        denom += es;
        #pragma unroll
        for (int i = 0; i < 8; ++i) acc[i] += es * bf2f((unsigned short)vv[i]);
    }
    #pragma unroll
    for (int off = 16; off < 64; off <<= 1) {
        denom += __shfl_xor(denom, off);
        #pragma unroll
        for (int i = 0; i < 8; ++i) acc[i] += __shfl_xor(acc[i], off);
    }
    if (slot == 0) {
        float inv = 1.f / (denom + 1e-10f);
        float4 o0 = make_float4(acc[0]*inv, acc[1]*inv, acc[2]*inv, acc[3]*inv);
        float4 o1 = make_float4(acc[4]*inv, acc[5]*inv, acc[6]*inv, acc[7]*inv);
        *(float4*)(out + (size_t)node * HID + j * 8)     = o0;
        *(float4*)(out + (size_t)node * HID + j * 8 + 4) = o1;
    }
}

// ---------------- final projection via bf16 MFMA, in place on d_out ----------------
__global__ __launch_bounds__(256) void k_outproj_mfma(
    float* __restrict__ io, const unsigned short* __restrict__ wbf,
    const float* __restrict__ ob, int n)
{
    __shared__ unsigned short hs[64][136];
    int t = threadIdx.x;
    int m0 = blockIdx.x * 64;
    #pragma unroll
    for (int p = 0; p < 2; ++p) {
        int f = p * 256 + t;
        int r = f >> 3;
        int c16 = (f & 7) * 16;
        int node = m0 + r;
        float4 u0 = {0,0,0,0}, u1 = {0,0,0,0}, u2 = {0,0,0,0}, u3 = {0,0,0,0};
        if (node < n) {
            const float4* px = (const float4*)(io + (size_t)node * HID + c16);
            u0 = px[0]; u1 = px[1]; u2 = px[2]; u3 = px[3];
        }
        union { unsigned short u[8]; short8 v; } a, b;
        a.u[0]=f2bf(u0.x); a.u[1]=f2bf(u0.y); a.u[2]=f2bf(u0.z); a.u[3]=f2bf(u0.w);
        a.u[4]=f2bf(u1.x); a.u[5]=f2bf(u1.y); a.u[6]=f2bf(u1.z); a.u[7]=f2bf(u1.w);
        b.u[0]=f2bf(u2.x); b.u[1]=f2bf(u2.y); b.u[2]=f2bf(u2.z); b.u[3]=f2bf(u2.w);
        b.u[4]=f2bf(u3.x); b.u[5]=f2bf(u3.y); b.u[6]=f2bf(u3.z); b.u[7]=f2bf(u3.w);
        *(short8*)&hs[r][c16]     = a.v;
        *(short8*)&hs[r][c16 + 8] = b.v;
    }
    __syncthreads();

    int w = t >> 6, l = t & 63;
    int lr = l & 15, lc = l >> 4;
    short8 afr[4];
    #pragma unroll
    for (int c = 0; c < 4; ++c)
        afr[c] = *(const short8*)&hs[w * 16 + lr][c * 32 + lc * 8];

    #pragma unroll
    for (int ct = 0; ct < 8; ++ct) {
        int colg = ct * 16 + lr;
        f32x4 acc = {0.f, 0.f, 0.f, 0.f};
        const unsigned short* wrow = wbf + (size_t)3 * 16384 + (size_t)colg * 128 + lc * 8;
        #pragma unroll
        for (int c = 0; c < 4; ++c) {
            short8 bfr = *(const short8*)(wrow + c * 32);
            acc = __builtin_amdgcn_mfma_f32_16x16x32_bf16(afr[c], bfr, acc, 0, 0, 0);
        }
        float bv = ob[colg];
        #pragma unroll
        for (int r = 0; r < 4; ++r) {
            int node = m0 + w * 16 + lc * 4 + r;
            if (node < n)
                io[(size_t)node * HID + colg] = acc[r] + bv;
        }
    }
}

extern "C" void kernel_launch(void* const* d_in, const int* in_sizes, int n_in,
                              void* d_out, int out_size, void* d_ws, size_t ws_size,
                              hipStream_t stream) {
    const float* x   = (const float*)d_in[0];
    const int*   eix = (const int*)  d_in[1];
    const float* emb = (const float*)d_in[2];
    const float* qw  = (const float*)d_in[3];
    const float* qb  = (const float*)d_in[4];
    const float* kw  = (const float*)d_in[5];
    const float* kb  = (const float*)d_in[6];
    const float* vw  = (const float*)d_in[7];
    const float* vb  = (const float*)d_in[8];
    const float* ow  = (const float*)d_in[9];
    const float* ob  = (const float*)d_in[10];
    const float* ebw = (const float*)d_in[11];
    const float* ebb = (const float*)d_in[12];

    int n = in_sizes[0] / HID;
    int E = in_sizes[2] / HID;
    const int* row = eix;
    const int* col = eix + E;

    char* wsp = (char*)d_ws;
    auto alloc = [&](size_t bytes) -> void* {
        void* p = (void*)wsp;
        wsp += (bytes + 255) & ~(size_t)255;
        return p;
    };
    unsigned short* qkvbf = (unsigned short*)alloc((size_t)n * 384 * 2);
    unsigned short* wbf   = (unsigned short*)alloc((size_t)4 * 16384 * 2);
    float* ebias_s        = (float*)alloc((size_t)E * NH * 4);
    int* count            = (int*)alloc((size_t)(n + 2) * 4);
    int* startp           = (int*)alloc((size_t)(n + 2) * 4);
    int* bsums            = (int*)alloc(256 * 4);
    int* cursor           = (int*)alloc((size_t)n * 4);
    int* col_sorted       = (int*)alloc((size_t)E * 4);

    hipMemsetAsync(count, 0, (size_t)(n + 1) * sizeof(int), stream);
    hipMemsetAsync(cursor, 0, (size_t)n * sizeof(int), stream);

    k_cvtw<<<64, 256, 0, stream>>>(qw, kw, vw, ow, wbf);
    k_hist<<<2048, 256, 0, stream>>>(row, E, count);

    int total = n + 1;
    int nb = (total + 1023) / 1024;
    k_scan1<<<nb, 256, 0, stream>>>(count, total, startp, bsums);
    k_scan2<<<1, 128, 0, stream>>>(bsums, nb);
    k_scan3<<<nb, 256, 0, stream>>>(startp, total, bsums);

    k_edge_fused<<<2048, 256, 0, stream>>>(row, col, emb, ebw, ebb, startp,
                                           cursor, col_sorted, ebias_s, E);

    k_qkv_mfma<<<(n + 63) / 64, 256, 0, stream>>>(x, wbf, qb, kb, vb, qkvbf, n);
    k_attn<<<(n + 3) / 4, 256, 0, stream>>>(qkvbf, ebias_s, col_sorted, startp,
                                            (float*)d_out, n, E);
    k_outproj_mfma<<<(n + 63) / 64, 256, 0, stream>>>((float*)d_out, wbf, ob, n);
}

// Round 5
// 570.366 us; speedup vs baseline: 1.6545x; 1.0003x over previous
//
#include <hip/hip_runtime.h>

#define HID 128
#define NH 8

typedef __attribute__((ext_vector_type(8))) short short8;
typedef __attribute__((ext_vector_type(4))) float f32x4;

__device__ __forceinline__ unsigned short f2bf(float f) {
    unsigned int u = __float_as_uint(f);
    u = (u + 0x7FFF + ((u >> 16) & 1)) >> 16;
    return (unsigned short)u;
}
__device__ __forceinline__ float bf2f(unsigned short s) {
    return __uint_as_float((unsigned int)s << 16);
}

// ---------------- histogram of destination rows ----------------
__global__ void k_hist(const int* __restrict__ row, int E, int* __restrict__ count) {
    int i = blockIdx.x * blockDim.x + threadIdx.x;
    int stride = gridDim.x * blockDim.x;
    for (; i < E; i += stride) atomicAdd(&count[row[i]], 1);
}

// ---------------- 3-phase exclusive scan ----------------
__global__ void k_scan1(const int* __restrict__ in, int total,
                        int* __restrict__ out, int* __restrict__ bsums) {
    __shared__ int sd[256];
    int t = threadIdx.x;
    int base = blockIdx.x * 1024 + t * 4;
    int v0 = (base + 0 < total) ? in[base + 0] : 0;
    int v1 = (base + 1 < total) ? in[base + 1] : 0;
    int v2 = (base + 2 < total) ? in[base + 2] : 0;
    int v3 = (base + 3 < total) ? in[base + 3] : 0;
    int s = v0 + v1 + v2 + v3;
    sd[t] = s; __syncthreads();
    for (int off = 1; off < 256; off <<= 1) {
        int xx = (t >= off) ? sd[t - off] : 0;
        __syncthreads();
        sd[t] += xx;
        __syncthreads();
    }
    int excl = sd[t] - s;
    if (t == 255) bsums[blockIdx.x] = sd[255];
    int run = excl;
    if (base + 0 < total) out[base + 0] = run; run += v0;
    if (base + 1 < total) out[base + 1] = run; run += v1;
    if (base + 2 < total) out[base + 2] = run; run += v2;
    if (base + 3 < total) out[base + 3] = run;
}

__global__ void k_scan2(int* __restrict__ bs, int nb) {
    __shared__ int sd[128];
    int t = threadIdx.x;
    int vv = (t < nb) ? bs[t] : 0;
    sd[t] = vv; __syncthreads();
    for (int off = 1; off < 128; off <<= 1) {
        int xx = (t >= off) ? sd[t - off] : 0;
        __syncthreads();
        sd[t] += xx;
        __syncthreads();
    }
    if (t < nb) bs[t] = sd[t] - vv;   // exclusive
}

__global__ void k_scan3(int* __restrict__ out, int total, const int* __restrict__ bs) {
    int add = bs[blockIdx.x];
    int base = blockIdx.x * 1024 + threadIdx.x * 4;
    #pragma unroll
    for (int i = 0; i < 4; ++i)
        if (base + i < total) out[base + i] += add;
}

// ---------------- fused: edge-bias GEMV + sorted scatter of (col, bias) ----------------
__global__ __launch_bounds__(256) void k_edge_fused(
    const int* __restrict__ row, const int* __restrict__ col,
    const float* __restrict__ emb, const float* __restrict__ ebw,
    const float* __restrict__ ebb, const int* __restrict__ start,
    int* __restrict__ cursor, int* __restrict__ col_sorted,
    float* __restrict__ ebias_s, int E)
{
    __shared__ float Wx[8][4][8][4];   // [h][c][g][j] = ebw[h*128 + g*16 + c*4 + j]
    __shared__ float bb[8];
    int t = threadIdx.x;
    for (int i = t; i < 1024; i += 256) {
        int j = i & 3, g = (i >> 2) & 7, c = (i >> 5) & 3, h = i >> 7;
        Wx[h][c][g][j] = ebw[h * 128 + g * 16 + c * 4 + j];
    }
    if (t < 8) bb[t] = ebb[t];
    __syncthreads();

    int l = t & 63;
    int g = l & 7;        // column-chunk group
    int sub = l >> 3;     // edge within wave's group of 8
    int wid = blockIdx.x * 4 + (t >> 6);
    int nwaves = gridDim.x * 4;

    for (int base = wid * 8; base < E; base += nwaves * 8) {
        int e = base + sub;
        bool act = e < E;
        float p[8] = {0.f,0.f,0.f,0.f,0.f,0.f,0.f,0.f};
        if (act) {
            const float4* pe = (const float4*)(emb + (size_t)e * HID + g * 16);
            #pragma unroll
            for (int c = 0; c < 4; ++c) {
                float4 ev = pe[c];
                #pragma unroll
                for (int h = 0; h < 8; ++h) {
                    float4 wv = *(const float4*)&Wx[h][c][g][0];
                    p[h] += ev.x*wv.x + ev.y*wv.y + ev.z*wv.z + ev.w*wv.w;
                }
            }
        }
        #pragma unroll
        for (int off = 1; off < 8; off <<= 1) {
            #pragma unroll
            for (int h = 0; h < 8; ++h) p[h] += __shfl_xor(p[h], off);
        }
        int pslot = 0;
        if (act && g == 0) {
            int r = row[e];
            pslot = start[r] + atomicAdd(&cursor[r], 1);
            col_sorted[pslot] = col[e];
        }
        pslot = __shfl(pslot, l & 56);   // broadcast from lane sub*8
        if (act) ebias_s[(size_t)pslot * NH + g] = p[g] + bb[g];
    }
}

// ---------------- convert the 4 weight matrices to bf16 ----------------
__global__ void k_cvtw(const float* __restrict__ qw, const float* __restrict__ kw,
                       const float* __restrict__ vw, const float* __restrict__ ow,
                       unsigned short* __restrict__ wbf) {
    int i = blockIdx.x * 256 + threadIdx.x;
    int idx = i * 4;
    int m = idx >> 14;
    int off = idx & 16383;
    const float* src = (m == 0) ? qw : (m == 1) ? kw : (m == 2) ? vw : ow;
    float4 v = *(const float4*)(src + off);
    ushort4 o;
    o.x = f2bf(v.x); o.y = f2bf(v.y); o.z = f2bf(v.z); o.w = f2bf(v.w);
    *(ushort4*)(wbf + idx) = o;
}

// ---------------- QKV projection via bf16 MFMA: qkv[node][384] bf16 ----------------
__global__ __launch_bounds__(256) void k_qkv_mfma(
    const float* __restrict__ x, const unsigned short* __restrict__ wbf,
    const float* __restrict__ qb, const float* __restrict__ kb, const float* __restrict__ vb,
    unsigned short* __restrict__ qkvbf, int n)
{
    __shared__ unsigned short xs[64][136];
    int t = threadIdx.x;
    int m0 = blockIdx.x * 64;
    #pragma unroll
    for (int p = 0; p < 2; ++p) {
        int f = p * 256 + t;
        int r = f >> 3;
        int c16 = (f & 7) * 16;
        int node = m0 + r;
        float4 u0 = {0,0,0,0}, u1 = {0,0,0,0}, u2 = {0,0,0,0}, u3 = {0,0,0,0};
        if (node < n) {
            const float4* px = (const float4*)(x + (size_t)node * HID + c16);
            u0 = px[0]; u1 = px[1]; u2 = px[2]; u3 = px[3];
        }
        union { unsigned short u[8]; short8 v; } a, b;
        a.u[0]=f2bf(u0.x); a.u[1]=f2bf(u0.y); a.u[2]=f2bf(u0.z); a.u[3]=f2bf(u0.w);
        a.u[4]=f2bf(u1.x); a.u[5]=f2bf(u1.y); a.u[6]=f2bf(u1.z); a.u[7]=f2bf(u1.w);
        b.u[0]=f2bf(u2.x); b.u[1]=f2bf(u2.y); b.u[2]=f2bf(u2.z); b.u[3]=f2bf(u2.w);
        b.u[4]=f2bf(u3.x); b.u[5]=f2bf(u3.y); b.u[6]=f2bf(u3.z); b.u[7]=f2bf(u3.w);
        *(short8*)&xs[r][c16]     = a.v;
        *(short8*)&xs[r][c16 + 8] = b.v;
    }
    __syncthreads();

    int w = t >> 6, l = t & 63;
    int lr = l & 15, lc = l >> 4;
    short8 afr[4];
    #pragma unroll
    for (int c = 0; c < 4; ++c)
        afr[c] = *(const short8*)&xs[w * 16 + lr][c * 32 + lc * 8];

    #pragma unroll
    for (int m = 0; m < 3; ++m) {
        const float* bias = (m == 0) ? qb : (m == 1) ? kb : vb;
        #pragma unroll
        for (int ct = 0; ct < 8; ++ct) {
            int colg = ct * 16 + lr;
            f32x4 acc = {0.f, 0.f, 0.f, 0.f};
            const unsigned short* wrow = wbf + (size_t)m * 16384 + (size_t)colg * 128 + lc * 8;
            #pragma unroll
            for (int c = 0; c < 4; ++c) {
                short8 bfr = *(const short8*)(wrow + c * 32);
                acc = __builtin_amdgcn_mfma_f32_16x16x32_bf16(afr[c], bfr, acc, 0, 0, 0);
            }
            float bv = bias[colg];
            #pragma unroll
            for (int r = 0; r < 4; ++r) {
                int node = m0 + w * 16 + lc * 4 + r;
                if (node < n)
                    qkvbf[(size_t)node * 384 + m * 128 + colg] = f2bf(acc[r] + bv);
            }
        }
    }
}

// ---------------- per-node attention: lane = (edge-slot, head); no intra-loop shfl,
// no software pipeline, every variable initialized on every path ----------------
__global__ __launch_bounds__(256) void k_attn(
    const unsigned short* __restrict__ qkvbf, const float* __restrict__ ebs,
    const int* __restrict__ cols, const int* __restrict__ start,
    float* __restrict__ out, int n)
{
    int node = blockIdx.x * 4 + (threadIdx.x >> 6);
    if (node >= n) return;
    int l = threadIdx.x & 63;
    int slot = l >> 3;   // edge slot 0..7
    int h = l & 7;       // head 0..7
    int s0 = start[node];
    int deg = start[node + 1] - s0;

    float qf[16];
    {
        const unsigned short* qp = qkvbf + (size_t)node * 384 + h * 16;
        short8 q0 = *(const short8*)qp;
        short8 q1 = *(const short8*)(qp + 8);
        #pragma unroll
        for (int i = 0; i < 8; ++i) {
            qf[i] = bf2f((unsigned short)q0[i]);
            qf[8 + i] = bf2f((unsigned short)q1[i]);
        }
    }

    float acc[16];
    #pragma unroll
    for (int i = 0; i < 16; ++i) acc[i] = 0.f;
    float denom = 0.f;

    for (int base = 0; base < deg; base += 8) {
        int idx = base + slot;
        bool act = idx < deg;
        int c = act ? cols[s0 + idx] : 0;
        const unsigned short* kv = qkvbf + (size_t)c * 384 + 128 + h * 16;
        short8 ka  = *(const short8*)kv;
        short8 kbv = *(const short8*)(kv + 8);
        short8 va  = *(const short8*)(kv + 128);
        short8 vb  = *(const short8*)(kv + 136);
        float eb = act ? ebs[(size_t)(s0 + idx) * NH + h] : 0.f;
        float part = 0.f;
        #pragma unroll
        for (int i = 0; i < 8; ++i) part += qf[i] * bf2f((unsigned short)ka[i]);
        #pragma unroll
        for (int i = 0; i < 8; ++i) part += qf[8 + i] * bf2f((unsigned short)kbv[i]);
        float es = act ? __expf(part * 0.25f + eb) : 0.f;
        denom += es;
        #pragma unroll
        for (int i = 0; i < 8; ++i) acc[i]     += es * bf2f((unsigned short)va[i]);
        #pragma unroll
        for (int i = 0; i < 8; ++i) acc[8 + i] += es * bf2f((unsigned short)vb[i]);
    }

    // reduce across the 8 edge slots (head h = bits 0..2 preserved; slot = bits 3..5)
    #pragma unroll
    for (int off = 8; off < 64; off <<= 1) {
        denom += __shfl_xor(denom, off);
        #pragma unroll
        for (int i = 0; i < 16; ++i) acc[i] += __shfl_xor(acc[i], off);
    }
    if (slot == 0) {
        float inv = 1.f / (denom + 1e-10f);
        float* op = out + (size_t)node * HID + h * 16;
        #pragma unroll
        for (int c = 0; c < 4; ++c) {
            float4 o = make_float4(acc[c*4]*inv, acc[c*4+1]*inv, acc[c*4+2]*inv, acc[c*4+3]*inv);
            *(float4*)(op + c * 4) = o;
        }
    }
}

// ---------------- final projection via bf16 MFMA, in place on d_out ----------------
__global__ __launch_bounds__(256) void k_outproj_mfma(
    float* __restrict__ io, const unsigned short* __restrict__ wbf,
    const float* __restrict__ ob, int n)
{
    __shared__ unsigned short hs[64][136];
    int t = threadIdx.x;
    int m0 = blockIdx.x * 64;
    #pragma unroll
    for (int p = 0; p < 2; ++p) {
        int f = p * 256 + t;
        int r = f >> 3;
        int c16 = (f & 7) * 16;
        int node = m0 + r;
        float4 u0 = {0,0,0,0}, u1 = {0,0,0,0}, u2 = {0,0,0,0}, u3 = {0,0,0,0};
        if (node < n) {
            const float4* px = (const float4*)(io + (size_t)node * HID + c16);
            u0 = px[0]; u1 = px[1]; u2 = px[2]; u3 = px[3];
        }
        union { unsigned short u[8]; short8 v; } a, b;
        a.u[0]=f2bf(u0.x); a.u[1]=f2bf(u0.y); a.u[2]=f2bf(u0.z); a.u[3]=f2bf(u0.w);
        a.u[4]=f2bf(u1.x); a.u[5]=f2bf(u1.y); a.u[6]=f2bf(u1.z); a.u[7]=f2bf(u1.w);
        b.u[0]=f2bf(u2.x); b.u[1]=f2bf(u2.y); b.u[2]=f2bf(u2.z); b.u[3]=f2bf(u2.w);
        b.u[4]=f2bf(u3.x); b.u[5]=f2bf(u3.y); b.u[6]=f2bf(u3.z); b.u[7]=f2bf(u3.w);
        *(short8*)&hs[r][c16]     = a.v;
        *(short8*)&hs[r][c16 + 8] = b.v;
    }
    __syncthreads();

    int w = t >> 6, l = t & 63;
    int lr = l & 15, lc = l >> 4;
    short8 afr[4];
    #pragma unroll
    for (int c = 0; c < 4; ++c)
        afr[c] = *(const short8*)&hs[w * 16 + lr][c * 32 + lc * 8];

    #pragma unroll
    for (int ct = 0; ct < 8; ++ct) {
        int colg = ct * 16 + lr;
        f32x4 acc = {0.f, 0.f, 0.f, 0.f};
        const unsigned short* wrow = wbf + (size_t)3 * 16384 + (size_t)colg * 128 + lc * 8;
        #pragma unroll
        for (int c = 0; c < 4; ++c) {
            short8 bfr = *(const short8*)(wrow + c * 32);
            acc = __builtin_amdgcn_mfma_f32_16x16x32_bf16(afr[c], bfr, acc, 0, 0, 0);
        }
        float bv = ob[colg];
        #pragma unroll
        for (int r = 0; r < 4; ++r) {
            int node = m0 + w * 16 + lc * 4 + r;
            if (node < n)
                io[(size_t)node * HID + colg] = acc[r] + bv;
        }
    }
}

extern "C" void kernel_launch(void* const* d_in, const int* in_sizes, int n_in,
                              void* d_out, int out_size, void* d_ws, size_t ws_size,
                              hipStream_t stream) {
    const float* x   = (const float*)d_in[0];
    const int*   eix = (const int*)  d_in[1];
    const float* emb = (const float*)d_in[2];
    const float* qw  = (const float*)d_in[3];
    const float* qb  = (const float*)d_in[4];
    const float* kw  = (const float*)d_in[5];
    const float* kb  = (const float*)d_in[6];
    const float* vw  = (const float*)d_in[7];
    const float* vb  = (const float*)d_in[8];
    const float* ow  = (const float*)d_in[9];
    const float* ob  = (const float*)d_in[10];
    const float* ebw = (const float*)d_in[11];
    const float* ebb = (const float*)d_in[12];

    int n = in_sizes[0] / HID;
    int E = in_sizes[2] / HID;
    const int* row = eix;
    const int* col = eix + E;

    char* wsp = (char*)d_ws;
    auto alloc = [&](size_t bytes) -> void* {
        void* p = (void*)wsp;
        wsp += (bytes + 255) & ~(size_t)255;
        return p;
    };
    unsigned short* qkvbf = (unsigned short*)alloc((size_t)n * 384 * 2);
    unsigned short* wbf   = (unsigned short*)alloc((size_t)4 * 16384 * 2);
    float* ebias_s        = (float*)alloc((size_t)E * NH * 4);
    int* count            = (int*)alloc((size_t)(n + 2) * 4);
    int* startp           = (int*)alloc((size_t)(n + 2) * 4);
    int* bsums            = (int*)alloc(256 * 4);
    int* cursor           = (int*)alloc((size_t)n * 4);
    int* col_sorted       = (int*)alloc((size_t)E * 4);

    hipMemsetAsync(count, 0, (size_t)(n + 1) * sizeof(int), stream);
    hipMemsetAsync(cursor, 0, (size_t)n * sizeof(int), stream);

    k_cvtw<<<64, 256, 0, stream>>>(qw, kw, vw, ow, wbf);
    k_hist<<<2048, 256, 0, stream>>>(row, E, count);

    int total = n + 1;
    int nb = (total + 1023) / 1024;
    k_scan1<<<nb, 256, 0, stream>>>(count, total, startp, bsums);
    k_scan2<<<1, 128, 0, stream>>>(bsums, nb);
    k_scan3<<<nb, 256, 0, stream>>>(startp, total, bsums);

    k_edge_fused<<<2048, 256, 0, stream>>>(row, col, emb, ebw, ebb, startp,
                                           cursor, col_sorted, ebias_s, E);

    k_qkv_mfma<<<(n + 63) / 64, 256, 0, stream>>>(x, wbf, qb, kb, vb, qkvbf, n);
    k_attn<<<(n + 3) / 4, 256, 0, stream>>>(qkvbf, ebias_s, col_sorted, startp,
                                            (float*)d_out, n);
    k_outproj_mfma<<<(n + 63) / 64, 256, 0, stream>>>((float*)d_out, wbf, ob, n);
}

// Round 6
// 564.340 us; speedup vs baseline: 1.6721x; 1.0107x over previous
//
#include <hip/hip_runtime.h>

#define HID 128
#define NH 8

typedef __attribute__((ext_vector_type(8))) short short8;
typedef __attribute__((ext_vector_type(4))) float f32x4;

__device__ __forceinline__ unsigned short f2bf(float f) {
    unsigned int u = __float_as_uint(f);
    u = (u + 0x7FFF + ((u >> 16) & 1)) >> 16;
    return (unsigned short)u;
}
__device__ __forceinline__ float bf2f(unsigned short s) {
    return __uint_as_float((unsigned int)s << 16);
}
__device__ __forceinline__ unsigned int pack2bf(float lo, float hi) {
    return (unsigned int)f2bf(lo) | ((unsigned int)f2bf(hi) << 16);
}

// ---------------- histogram of destination rows ----------------
__global__ void k_hist(const int* __restrict__ row, int E, int* __restrict__ count) {
    int i = blockIdx.x * blockDim.x + threadIdx.x;
    int stride = gridDim.x * blockDim.x;
    for (; i < E; i += stride) atomicAdd(&count[row[i]], 1);
}

// ---------------- 3-phase exclusive scan ----------------
__global__ void k_scan1(const int* __restrict__ in, int total,
                        int* __restrict__ out, int* __restrict__ bsums) {
    __shared__ int sd[256];
    int t = threadIdx.x;
    int base = blockIdx.x * 1024 + t * 4;
    int v0 = (base + 0 < total) ? in[base + 0] : 0;
    int v1 = (base + 1 < total) ? in[base + 1] : 0;
    int v2 = (base + 2 < total) ? in[base + 2] : 0;
    int v3 = (base + 3 < total) ? in[base + 3] : 0;
    int s = v0 + v1 + v2 + v3;
    sd[t] = s; __syncthreads();
    for (int off = 1; off < 256; off <<= 1) {
        int xx = (t >= off) ? sd[t - off] : 0;
        __syncthreads();
        sd[t] += xx;
        __syncthreads();
    }
    int excl = sd[t] - s;
    if (t == 255) bsums[blockIdx.x] = sd[255];
    int run = excl;
    if (base + 0 < total) out[base + 0] = run; run += v0;
    if (base + 1 < total) out[base + 1] = run; run += v1;
    if (base + 2 < total) out[base + 2] = run; run += v2;
    if (base + 3 < total) out[base + 3] = run;
}

__global__ void k_scan2(int* __restrict__ bs, int nb) {
    __shared__ int sd[128];
    int t = threadIdx.x;
    int vv = (t < nb) ? bs[t] : 0;
    sd[t] = vv; __syncthreads();
    for (int off = 1; off < 128; off <<= 1) {
        int xx = (t >= off) ? sd[t - off] : 0;
        __syncthreads();
        sd[t] += xx;
        __syncthreads();
    }
    if (t < nb) bs[t] = sd[t] - vv;   // exclusive
}

__global__ void k_scan3(int* __restrict__ out, int total, const int* __restrict__ bs) {
    int add = bs[blockIdx.x];
    int base = blockIdx.x * 1024 + threadIdx.x * 4;
    #pragma unroll
    for (int i = 0; i < 4; ++i)
        if (base + i < total) out[base + i] += add;
}

// ---------------- convert the 4 weight matrices to bf16 ----------------
__global__ void k_cvtw(const float* __restrict__ qw, const float* __restrict__ kw,
                       const float* __restrict__ vw, const float* __restrict__ ow,
                       unsigned short* __restrict__ wbf) {
    int i = blockIdx.x * 256 + threadIdx.x;
    int idx = i * 4;
    int m = idx >> 14;
    int off = idx & 16383;
    const float* src = (m == 0) ? qw : (m == 1) ? kw : (m == 2) ? vw : ow;
    float4 v = *(const float4*)(src + off);
    ushort4 o;
    o.x = f2bf(v.x); o.y = f2bf(v.y); o.z = f2bf(v.z); o.w = f2bf(v.w);
    *(ushort4*)(wbf + idx) = o;
}

// ---------------- FAT kernel: qkv-MFMA blocks first, then edge blocks ----------------
// qkv blocks [0, qb): project 64 nodes each, write qkv[node][384] bf16.
// edge blocks [qb, qb+eb): 32 edges each — edge-bias GEMV, claim sorted slot,
//   write one 32B record per edge: { int col; bf16 bias[8]; pad }.
__global__ __launch_bounds__(256) void k_fat(
    const float* __restrict__ x, const unsigned short* __restrict__ wbf,
    const float* __restrict__ qb_, const float* __restrict__ kb_, const float* __restrict__ vb_,
    unsigned short* __restrict__ qkvbf, int n, int qblocks,
    const int* __restrict__ row, const int* __restrict__ col,
    const float* __restrict__ emb, const float* __restrict__ ebw,
    const float* __restrict__ ebb, const int* __restrict__ start,
    int* __restrict__ cursor, char* __restrict__ recs, int E)
{
    __shared__ __align__(16) char sm[17408];
    int bid = blockIdx.x;
    int t = threadIdx.x;

    if (bid < qblocks) {
        // ---------- QKV projection ----------
        unsigned short (*xs)[136] = (unsigned short (*)[136])sm;
        int m0 = bid * 64;
        #pragma unroll
        for (int p = 0; p < 2; ++p) {
            int f = p * 256 + t;
            int r = f >> 3;
            int c16 = (f & 7) * 16;
            int node = m0 + r;
            float4 u0 = {0,0,0,0}, u1 = {0,0,0,0}, u2 = {0,0,0,0}, u3 = {0,0,0,0};
            if (node < n) {
                const float4* px = (const float4*)(x + (size_t)node * HID + c16);
                u0 = px[0]; u1 = px[1]; u2 = px[2]; u3 = px[3];
            }
            union { unsigned short u[8]; short8 v; } a, b;
            a.u[0]=f2bf(u0.x); a.u[1]=f2bf(u0.y); a.u[2]=f2bf(u0.z); a.u[3]=f2bf(u0.w);
            a.u[4]=f2bf(u1.x); a.u[5]=f2bf(u1.y); a.u[6]=f2bf(u1.z); a.u[7]=f2bf(u1.w);
            b.u[0]=f2bf(u2.x); b.u[1]=f2bf(u2.y); b.u[2]=f2bf(u2.z); b.u[3]=f2bf(u2.w);
            b.u[4]=f2bf(u3.x); b.u[5]=f2bf(u3.y); b.u[6]=f2bf(u3.z); b.u[7]=f2bf(u3.w);
            *(short8*)&xs[r][c16]     = a.v;
            *(short8*)&xs[r][c16 + 8] = b.v;
        }
        __syncthreads();

        int w = t >> 6, l = t & 63;
        int lr = l & 15, lc = l >> 4;
        short8 afr[4];
        #pragma unroll
        for (int c = 0; c < 4; ++c)
            afr[c] = *(const short8*)&xs[w * 16 + lr][c * 32 + lc * 8];

        #pragma unroll
        for (int m = 0; m < 3; ++m) {
            const float* bias = (m == 0) ? qb_ : (m == 1) ? kb_ : vb_;
            #pragma unroll
            for (int ct = 0; ct < 8; ++ct) {
                int colg = ct * 16 + lr;
                f32x4 acc = {0.f, 0.f, 0.f, 0.f};
                const unsigned short* wrow = wbf + (size_t)m * 16384 + (size_t)colg * 128 + lc * 8;
                #pragma unroll
                for (int c = 0; c < 4; ++c) {
                    short8 bfr = *(const short8*)(wrow + c * 32);
                    acc = __builtin_amdgcn_mfma_f32_16x16x32_bf16(afr[c], bfr, acc, 0, 0, 0);
                }
                float bv = bias[colg];
                #pragma unroll
                for (int r = 0; r < 4; ++r) {
                    int node = m0 + w * 16 + lc * 4 + r;
                    if (node < n)
                        qkvbf[(size_t)node * 384 + m * 128 + colg] = f2bf(acc[r] + bv);
                }
            }
        }
    } else {
        // ---------- edge-bias + sorted record scatter ----------
        float (*Wx)[4][8][4] = (float (*)[4][8][4])sm;   // [h][c][g][j], 4 KB
        for (int i = t; i < 1024; i += 256) {
            int j = i & 3, g = (i >> 2) & 7, c = (i >> 5) & 3, h = i >> 7;
            Wx[h][c][g][j] = ebw[h * 128 + g * 16 + c * 4 + j];
        }
        float bbr[8];
        #pragma unroll
        for (int i = 0; i < 8; ++i) bbr[i] = ebb[i];
        __syncthreads();

        int l = t & 63;
        int g = l & 7;        // column-chunk group
        int sub = l >> 3;     // edge within wave's group of 8
        int e = (bid - qblocks) * 32 + (t >> 6) * 8 + sub;
        bool act = e < E;

        float p[8] = {0.f,0.f,0.f,0.f,0.f,0.f,0.f,0.f};
        if (act) {
            const float4* pe = (const float4*)(emb + (size_t)e * HID + g * 16);
            #pragma unroll
            for (int c = 0; c < 4; ++c) {
                float4 ev = pe[c];
                #pragma unroll
                for (int h = 0; h < 8; ++h) {
                    float4 wv = *(const float4*)&Wx[h][c][g][0];
                    p[h] += ev.x*wv.x + ev.y*wv.y + ev.z*wv.z + ev.w*wv.w;
                }
            }
        }
        // butterfly over the 8 lanes of this edge: every lane ends with all 8 head sums
        #pragma unroll
        for (int off = 1; off < 8; off <<= 1) {
            #pragma unroll
            for (int h = 0; h < 8; ++h) p[h] += __shfl_xor(p[h], off);
        }
        if (act && g == 0) {
            int r = row[e];
            int ps = start[r] + atomicAdd(&cursor[r], 1);
            char* rp = recs + (size_t)ps * 32;
            uint4 r0;
            r0.x = (unsigned int)col[e];
            r0.y = pack2bf(p[0] + bbr[0], p[1] + bbr[1]);
            r0.z = pack2bf(p[2] + bbr[2], p[3] + bbr[3]);
            r0.w = pack2bf(p[4] + bbr[4], p[5] + bbr[5]);
            uint2 r1;
            r1.x = pack2bf(p[6] + bbr[6], p[7] + bbr[7]);
            r1.y = 0;
            *(uint4*)rp = r0;
            *(uint2*)(rp + 16) = r1;
        }
    }
}

// ---------------- per-node attention: lane = (edge-slot, head) ----------------
__global__ __launch_bounds__(256) void k_attn(
    const unsigned short* __restrict__ qkvbf, const char* __restrict__ recs,
    const int* __restrict__ start, unsigned short* __restrict__ aout, int n)
{
    int node = blockIdx.x * 4 + (threadIdx.x >> 6);
    if (node >= n) return;
    int l = threadIdx.x & 63;
    int slot = l >> 3;   // edge slot 0..7
    int h = l & 7;       // head 0..7
    int s0 = start[node];
    int deg = start[node + 1] - s0;

    float qf[16];
    {
        const unsigned short* qp = qkvbf + (size_t)node * 384 + h * 16;
        short8 q0 = *(const short8*)qp;
        short8 q1 = *(const short8*)(qp + 8);
        #pragma unroll
        for (int i = 0; i < 8; ++i) {
            qf[i] = bf2f((unsigned short)q0[i]);
            qf[8 + i] = bf2f((unsigned short)q1[i]);
        }
    }

    float acc[16];
    #pragma unroll
    for (int i = 0; i < 16; ++i) acc[i] = 0.f;
    float denom = 0.f;

    for (int base = 0; base < deg; base += 8) {
        int idx = base + slot;
        bool act = idx < deg;
        const char* rp = recs + (size_t)(s0 + (act ? idx : 0)) * 32;
        int c = act ? *(const int*)rp : 0;
        float eb = act ? bf2f(*(const unsigned short*)(rp + 4 + 2 * h)) : 0.f;
        const unsigned short* kv = qkvbf + (size_t)c * 384 + 128 + h * 16;
        short8 ka  = *(const short8*)kv;
        short8 kbv = *(const short8*)(kv + 8);
        short8 va  = *(const short8*)(kv + 128);
        short8 vb  = *(const short8*)(kv + 136);
        float part = 0.f;
        #pragma unroll
        for (int i = 0; i < 8; ++i) part += qf[i] * bf2f((unsigned short)ka[i]);
        #pragma unroll
        for (int i = 0; i < 8; ++i) part += qf[8 + i] * bf2f((unsigned short)kbv[i]);
        float es = act ? __expf(part * 0.25f + eb) : 0.f;
        denom += es;
        #pragma unroll
        for (int i = 0; i < 8; ++i) acc[i]     += es * bf2f((unsigned short)va[i]);
        #pragma unroll
        for (int i = 0; i < 8; ++i) acc[8 + i] += es * bf2f((unsigned short)vb[i]);
    }

    // reduce across the 8 edge slots (head h = bits 0..2 preserved; slot = bits 3..5)
    #pragma unroll
    for (int off = 8; off < 64; off <<= 1) {
        denom += __shfl_xor(denom, off);
        #pragma unroll
        for (int i = 0; i < 16; ++i) acc[i] += __shfl_xor(acc[i], off);
    }
    if (slot == 0) {
        float inv = 1.f / (denom + 1e-10f);
        uint4 o0, o1;
        o0.x = pack2bf(acc[0]*inv,  acc[1]*inv);
        o0.y = pack2bf(acc[2]*inv,  acc[3]*inv);
        o0.z = pack2bf(acc[4]*inv,  acc[5]*inv);
        o0.w = pack2bf(acc[6]*inv,  acc[7]*inv);
        o1.x = pack2bf(acc[8]*inv,  acc[9]*inv);
        o1.y = pack2bf(acc[10]*inv, acc[11]*inv);
        o1.z = pack2bf(acc[12]*inv, acc[13]*inv);
        o1.w = pack2bf(acc[14]*inv, acc[15]*inv);
        unsigned short* op = aout + (size_t)node * HID + h * 16;
        *(uint4*)op       = o0;
        *(uint4*)(op + 8) = o1;
    }
}

// ---------------- final projection via bf16 MFMA: aout(bf16) -> d_out(f32) ----------------
__global__ __launch_bounds__(256) void k_outproj_mfma(
    const unsigned short* __restrict__ aout, const unsigned short* __restrict__ wbf,
    const float* __restrict__ ob, float* __restrict__ out, int n)
{
    __shared__ unsigned short hs[64][136];
    int t = threadIdx.x;
    int m0 = blockIdx.x * 64;
    #pragma unroll
    for (int p = 0; p < 4; ++p) {
        int f = p * 256 + t;        // 1024 chunks of 8 shorts
        int r = f >> 4;
        int c8 = (f & 15) * 8;
        int node = m0 + r;
        short8 val = {0,0,0,0,0,0,0,0};
        if (node < n) val = *(const short8*)(aout + (size_t)node * HID + c8);
        *(short8*)&hs[r][c8] = val;
    }
    __syncthreads();

    int w = t >> 6, l = t & 63;
    int lr = l & 15, lc = l >> 4;
    short8 afr[4];
    #pragma unroll
    for (int c = 0; c < 4; ++c)
        afr[c] = *(const short8*)&hs[w * 16 + lr][c * 32 + lc * 8];

    #pragma unroll
    for (int ct = 0; ct < 8; ++ct) {
        int colg = ct * 16 + lr;
        f32x4 acc = {0.f, 0.f, 0.f, 0.f};
        const unsigned short* wrow = wbf + (size_t)3 * 16384 + (size_t)colg * 128 + lc * 8;
        #pragma unroll
        for (int c = 0; c < 4; ++c) {
            short8 bfr = *(const short8*)(wrow + c * 32);
            acc = __builtin_amdgcn_mfma_f32_16x16x32_bf16(afr[c], bfr, acc, 0, 0, 0);
        }
        float bv = ob[colg];
        #pragma unroll
        for (int r = 0; r < 4; ++r) {
            int node = m0 + w * 16 + lc * 4 + r;
            if (node < n)
                out[(size_t)node * HID + colg] = acc[r] + bv;
        }
    }
}

extern "C" void kernel_launch(void* const* d_in, const int* in_sizes, int n_in,
                              void* d_out, int out_size, void* d_ws, size_t ws_size,
                              hipStream_t stream) {
    const float* x   = (const float*)d_in[0];
    const int*   eix = (const int*)  d_in[1];
    const float* emb = (const float*)d_in[2];
    const float* qw  = (const float*)d_in[3];
    const float* qb  = (const float*)d_in[4];
    const float* kw  = (const float*)d_in[5];
    const float* kb  = (const float*)d_in[6];
    const float* vw  = (const float*)d_in[7];
    const float* vb  = (const float*)d_in[8];
    const float* ow  = (const float*)d_in[9];
    const float* ob  = (const float*)d_in[10];
    const float* ebw = (const float*)d_in[11];
    const float* ebb = (const float*)d_in[12];

    int n = in_sizes[0] / HID;
    int E = in_sizes[2] / HID;
    const int* row = eix;
    const int* col = eix + E;

    char* wsp = (char*)d_ws;
    auto alloc = [&](size_t bytes) -> void* {
        void* p = (void*)wsp;
        wsp += (bytes + 255) & ~(size_t)255;
        return p;
    };
    unsigned short* qkvbf = (unsigned short*)alloc((size_t)n * 384 * 2);
    unsigned short* wbf   = (unsigned short*)alloc((size_t)4 * 16384 * 2);
    char* recs            = (char*)alloc((size_t)E * 32);
    unsigned short* aout  = (unsigned short*)alloc((size_t)n * HID * 2);
    int* count            = (int*)alloc((size_t)(n + 2) * 4);
    int* startp           = (int*)alloc((size_t)(n + 2) * 4);
    int* bsums            = (int*)alloc(256 * 4);
    int* cursor           = (int*)alloc((size_t)n * 4);

    hipMemsetAsync(count, 0, (size_t)(n + 1) * sizeof(int), stream);
    hipMemsetAsync(cursor, 0, (size_t)n * sizeof(int), stream);

    k_cvtw<<<64, 256, 0, stream>>>(qw, kw, vw, ow, wbf);
    k_hist<<<2048, 256, 0, stream>>>(row, E, count);

    int total = n + 1;
    int nb = (total + 1023) / 1024;
    k_scan1<<<nb, 256, 0, stream>>>(count, total, startp, bsums);
    k_scan2<<<1, 128, 0, stream>>>(bsums, nb);
    k_scan3<<<nb, 256, 0, stream>>>(startp, total, bsums);

    int qblocks = (n + 63) / 64;
    int eblocks = (E + 31) / 32;
    k_fat<<<qblocks + eblocks, 256, 0, stream>>>(
        x, wbf, qb, kb, vb, qkvbf, n, qblocks,
        row, col, emb, ebw, ebb, startp, cursor, recs, E);

    k_attn<<<(n + 3) / 4, 256, 0, stream>>>(qkvbf, recs, startp, aout, n);
    k_outproj_mfma<<<(n + 63) / 64, 256, 0, stream>>>(aout, wbf, ob, (float*)d_out, n);
}